// Round 6
// baseline (125.842 us; speedup 1.0000x reference)
//
#include <hip/hip_runtime.h>
#include <hip/hip_bf16.h>
#include <math.h>

#define NPIX 4096

typedef __attribute__((ext_vector_type(8))) short s8;   // 8 x bf16 (4 VGPRs)
typedef __attribute__((ext_vector_type(4))) float f4;   // 4 x f32

static __device__ __forceinline__ unsigned packbf2(float a, float b) {
    union { __hip_bfloat162 h; unsigned u; } x;
    x.h = __float22bfloat162_rn(make_float2(a, b));
    return x.u;
}
static __device__ __forceinline__ float2 unpackbf2(unsigned u) {
    float lo = __uint_as_float(u << 16);
    float hi = __uint_as_float(u & 0xffff0000u);
    return make_float2(lo, hi);
}

// ---------------------------------------------------------------------------
// Kernel 1: prep — q,k projections (bf16) + bf16 copy of x. (verified R5)
// q pre-scaled by log2(e) so flash uses exp2 (v_exp_f32) directly.
// ---------------------------------------------------------------------------
__global__ __launch_bounds__(512) void prep_kernel(
    const float* __restrict__ x,
    const float* __restrict__ Wq, const float* __restrict__ bq,
    const float* __restrict__ Wk, const float* __restrict__ bk,
    __hip_bfloat16* __restrict__ qbf, __hip_bfloat16* __restrict__ kbf,
    __hip_bfloat16* __restrict__ xbf)
{
    __shared__ float Xp[64][65];
    int t = threadIdx.x;
    int lane = t & 63;
    int grp  = t >> 6;               // 0..7, wave-uniform
    int b  = blockIdx.x >> 6;
    int n0 = (blockIdx.x & 63) << 6;

    const float* xb = x + ((size_t)b << 18);
    __hip_bfloat16* xbb = xbf + ((size_t)b << 18);
#pragma unroll
    for (int u = 0; u < 8; ++u) {
        int c = grp + u * 8;
        float v = xb[((size_t)c << 12) + n0 + lane];
        Xp[c][lane] = v;
        xbb[((size_t)c << 12) + n0 + lane] = __float2bfloat16(v);
    }
    __syncthreads();

    float qa = bq[grp], ka = bk[grp];
    const float* wq = Wq + grp * 64;   // wave-uniform base -> s_load
    const float* wk = Wk + grp * 64;
#pragma unroll
    for (int c = 0; c < 64; ++c) {
        float xv = Xp[c][lane];
        qa = fmaf(wq[c], xv, qa);
        ka = fmaf(wk[c], xv, ka);
    }
    qa *= 1.4426950408889634f;         // fold log2(e)
    int pix = b * NPIX + n0 + lane;
    qbf[(size_t)pix * 8 + grp] = __float2bfloat16(qa);
    kbf[(size_t)pix * 8 + grp] = __float2bfloat16(ka);
}

// ---------------------------------------------------------------------------
// Kernel 2: flash partial. R6: i-tile halved to 32 queries -> acc 32 AGPRs,
// total regs ~105 <= 128 (occupancy steps at 64/128/256 per m69; R5's 144
// regs dropped HW to 2 waves/SIMD). (256,4) now safe: arch budget fits.
// Grid 2048 = sId(4, slowest) x b(4) x i-tile(128).
// ---------------------------------------------------------------------------
__global__ __launch_bounds__(256, 4) void flash_part_kernel(
    const __hip_bfloat16* __restrict__ qbf, const __hip_bfloat16* __restrict__ kbf,
    const __hip_bfloat16* __restrict__ xbf,
    __hip_bfloat16* __restrict__ Opart, float* __restrict__ Lp)
{
    // phase A: Xs [64][136] bf16 @0 (17408B) | PT[w] [32][40] bf16 @17408+w*2560
    // phase B: Osh [32][68] f32 @0 | Lsh [4][32] @17408
    __shared__ __align__(16) char pool[27648];
    unsigned short* Xs = (unsigned short*)pool;

    int t = threadIdx.x;
    int w    = t >> 6;
    int lane = t & 63;
    int quad = lane >> 4;
    int c16  = lane & 15;
    unsigned short* PTw = (unsigned short*)(pool + 17408 + w * 2560);

    int blk  = blockIdx.x;
    int sId  = blk >> 9;
    int rest = blk & 511;
    int b    = rest >> 7;
    int i0   = (rest & 127) << 5;
    int jbase = sId << 10;

    const s8 zero8 = {0, 0, 0, 0, 0, 0, 0, 0};
    const f4 zero4 = {0.f, 0.f, 0.f, 0.f};

    // Q B-frags (B[k=quad*8+dd][n=c16]); only quad0 holds real d (0..7)
    s8 qf[2];
#pragma unroll
    for (int it = 0; it < 2; ++it) {
        s8 qv = *(const s8*)(qbf + ((size_t)(b * NPIX + i0 + it * 16 + c16) << 3));
        qf[it] = (quad == 0) ? qv : zero8;
    }

    f4 acc[4][2];
    float l[2] = {0.f, 0.f};
#pragma unroll
    for (int it = 0; it < 2; ++it)
#pragma unroll
        for (int cm = 0; cm < 4; ++cm) acc[cm][it] = zero4;

    const __hip_bfloat16* kb = kbf + ((size_t)(b * NPIX) << 3);
    const unsigned short* xg = (const unsigned short*)xbf + ((size_t)b << 18);

    for (int tile = 0; tile < 8; ++tile) {
        int j0 = jbase + (tile << 7);

        __syncthreads();   // previous tile's Xs/PT readers done
        {
            int c = t >> 2, seg = t & 3;
            const uint4* src = (const uint4*)(xg + ((size_t)c << 12) + j0 + seg * 32);
            uint4* dst = (uint4*)(Xs + c * 136 + seg * 32);
#pragma unroll
            for (int u = 0; u < 4; ++u) dst[u] = src[u];
        }
        // K frags for this tile (L2-hot; latency hidden by co-resident waves)
        s8 kf0 = *(const s8*)(kb + ((size_t)(j0 + w * 32 + c16) << 3));
        s8 kf1 = *(const s8*)(kb + ((size_t)(j0 + w * 32 + 16 + c16) << 3));
        __syncthreads();   // Xs ready

        // scores + exp2 + publish, one it at a time
#pragma unroll
        for (int it = 0; it < 2; ++it) {
            f4 s0 = __builtin_amdgcn_mfma_f32_16x16x32_bf16(kf0, qf[it], zero4, 0, 0, 0);
            f4 s1 = __builtin_amdgcn_mfma_f32_16x16x32_bf16(kf1, qf[it], zero4, 0, 0, 0);
            float e00 = exp2f(s0[0]), e01 = exp2f(s0[1]);
            float e02 = exp2f(s0[2]), e03 = exp2f(s0[3]);
            float e10 = exp2f(s1[0]), e11 = exp2f(s1[1]);
            float e12 = exp2f(s1[2]), e13 = exp2f(s1[3]);
            l[it] += ((e00 + e01) + (e02 + e03)) + ((e10 + e11) + (e12 + e13));
            int i = it * 16 + c16;
            uint2 pk0, pk1;
            pk0.x = packbf2(e00, e01); pk0.y = packbf2(e02, e03);
            pk1.x = packbf2(e10, e11); pk1.y = packbf2(e12, e13);
            *(uint2*)(PTw + i * 40 + quad * 4) = pk0;          // jm=0
            *(uint2*)(PTw + i * 40 + 16 + quad * 4) = pk1;     // jm=1
        }

        // P·x (same-wave PT reads — lgkmcnt only)
        s8 pf[2];
#pragma unroll
        for (int it = 0; it < 2; ++it)
            pf[it] = *(const s8*)(PTw + (it * 16 + c16) * 40 + quad * 8);
#pragma unroll
        for (int cm = 0; cm < 4; ++cm) {
            s8 xf = *(const s8*)(Xs + (cm * 16 + c16) * 136 + w * 32 + quad * 8);
#pragma unroll
            for (int it = 0; it < 2; ++it)
                acc[cm][it] = __builtin_amdgcn_mfma_f32_16x16x32_bf16(xf, pf[it], acc[cm][it], 0, 0, 0);
        }
    }

    // ---------------- epilogue: sum 4 waves, store partial ----------------
    float* Osh = (float*)pool;                 // [32 i][68]
    float* Lsh = (float*)(pool + 17408);       // [4][32]

#pragma unroll
    for (int it = 0; it < 2; ++it) {
        l[it] += __shfl_xor(l[it], 16);
        l[it] += __shfl_xor(l[it], 32);
    }
    __syncthreads();
    if (quad == 0) {
#pragma unroll
        for (int it = 0; it < 2; ++it) Lsh[w * 32 + it * 16 + c16] = l[it];
    }

    for (int wv = 0; wv < 4; ++wv) {
        __syncthreads();
        if (w == wv) {
#pragma unroll
            for (int cm = 0; cm < 4; ++cm)
#pragma unroll
                for (int it = 0; it < 2; ++it) {
                    int i = it * 16 + c16;
                    int c = cm * 16 + quad * 4;
                    float4* dstp = (float4*)(Osh + i * 68 + c);
                    f4 v = acc[cm][it];
                    if (wv == 0) {
                        *dstp = make_float4(v[0], v[1], v[2], v[3]);
                    } else {
                        float4 o = *dstp;
                        *dstp = make_float4(o.x + v[0], o.y + v[1], o.z + v[2], o.w + v[3]);
                    }
                }
        }
    }
    __syncthreads();

    if (t < 32)
        Lp[(size_t)blk * 32 + t] = Lsh[t] + Lsh[32 + t] + Lsh[64 + t] + Lsh[96 + t];

    // store partial O as bf16: thread t -> row i = t>>3, cols [(t&7)*8, +8)
    {
        int i = t >> 3, c0 = (t & 7) << 3;
        const float* src = Osh + i * 68 + c0;
        uint4 pk;
        pk.x = packbf2(src[0], src[1]); pk.y = packbf2(src[2], src[3]);
        pk.z = packbf2(src[4], src[5]); pk.w = packbf2(src[6], src[7]);
        *(uint4*)(Opart + (size_t)blk * 2048 + i * 64 + c0) = pk;
    }
}

// ---------------------------------------------------------------------------
// Kernel 3: merge 4 partials (plain sums) + Wv projection + bias + residual.
// Grid 256 (b, 64-i tile), 512 threads. Flash blocks are 32-i now:
// fb(sId, gi) = sId*512 + b*128 + (gi>>5), row (gi&31).
// ---------------------------------------------------------------------------
__global__ __launch_bounds__(512) void merge_kernel(
    const __hip_bfloat16* __restrict__ Opart, const float* __restrict__ Lp,
    const float* __restrict__ Wv, const float* __restrict__ bv,
    const float* __restrict__ x, const float* __restrict__ gamma,
    float* __restrict__ out)
{
    __shared__ float Osh[64 * 68];
    __shared__ float Wvs[4096];
    __shared__ float LinvS[64];
    __shared__ float bvs[64];

    int t = threadIdx.x;
    int b  = blockIdx.x >> 6;
    int i0 = (blockIdx.x & 63) << 6;

    if (t < 64) {
        int gi = i0 + t;
        int fb = b * 128 + (gi >> 5);
        int r  = gi & 31;
        float lt = Lp[(size_t)(0 * 512 + fb) * 32 + r]
                 + Lp[(size_t)(1 * 512 + fb) * 32 + r]
                 + Lp[(size_t)(2 * 512 + fb) * 32 + r]
                 + Lp[(size_t)(3 * 512 + fb) * 32 + r];
        LinvS[t] = 1.0f / lt;
        bvs[t] = bv[t];
    }
    {
        const float4* wsrc = (const float4*)Wv;
        float4* wdst = (float4*)Wvs;
        wdst[t] = wsrc[t];
        wdst[t + 512] = wsrc[t + 512];
    }
    __syncthreads();

    // combine partials: thread t -> row i = t>>3, cols [(t&7)*8, +8)
    {
        int i = t >> 3, c0 = (t & 7) << 3;
        int gi = i0 + i;
        int fb = b * 128 + (gi >> 5);
        int r  = gi & 31;
        float o[8];
#pragma unroll
        for (int k = 0; k < 8; ++k) o[k] = 0.f;
#pragma unroll
        for (int sId = 0; sId < 4; ++sId) {
            size_t base = (size_t)(sId * 512 + fb) * 2048 + r * 64 + c0;
            uint4 pk = *(const uint4*)(Opart + base);
            float2 e0 = unpackbf2(pk.x), e1 = unpackbf2(pk.y);
            float2 e2 = unpackbf2(pk.z), e3 = unpackbf2(pk.w);
            o[0] += e0.x; o[1] += e0.y; o[2] += e1.x; o[3] += e1.y;
            o[4] += e2.x; o[5] += e2.y; o[6] += e3.x; o[7] += e3.y;
        }
        float* dst = Osh + i * 68 + c0;
        *(float4*)(dst + 0) = make_float4(o[0], o[1], o[2], o[3]);
        *(float4*)(dst + 4) = make_float4(o[4], o[5], o[6], o[7]);
    }
    __syncthreads();

    // projection: i = t&63 (lane), cg = t>>6 -> 8 output channels each
    {
        int i  = t & 63;
        int cg = t >> 6;
        float inv = LinvS[i];
        float res[8];
#pragma unroll
        for (int k = 0; k < 8; ++k) res[k] = 0.f;
#pragma unroll 4
        for (int cb = 0; cb < 16; ++cb) {
            float4 o = *(const float4*)(Osh + i * 68 + cb * 4);
#pragma unroll
            for (int k = 0; k < 8; ++k) {
                float4 wv4 = *(const float4*)(Wvs + (cg * 8 + k) * 64 + cb * 4);
                res[k] = fmaf(wv4.x, o.x, fmaf(wv4.y, o.y, fmaf(wv4.z, o.z, fmaf(wv4.w, o.w, res[k]))));
            }
        }
        float g = gamma[0];
        const float* xr = x + ((size_t)b << 18) + i0;
        float* outp = out + ((size_t)b << 18) + i0;
#pragma unroll
        for (int k = 0; k < 8; ++k) {
            int c = cg * 8 + k;
            float attn = fmaf(res[k], inv, bvs[c]);
            size_t off = ((size_t)c << 12) + i;
            outp[off] = fmaf(g, attn, xr[off]);
        }
    }
}

extern "C" void kernel_launch(void* const* d_in, const int* in_sizes, int n_in,
                              void* d_out, int out_size, void* d_ws, size_t ws_size,
                              hipStream_t stream) {
    const float* x     = (const float*)d_in[0];
    const float* Wq    = (const float*)d_in[1];
    const float* bq    = (const float*)d_in[2];
    const float* Wk    = (const float*)d_in[3];
    const float* bk    = (const float*)d_in[4];
    const float* Wv    = (const float*)d_in[5];
    const float* bv    = (const float*)d_in[6];
    const float* gamma = (const float*)d_in[7];
    float* out = (float*)d_out;

    // ws: qbf 256KB | kbf 256KB | xbf 2MB | Opart 8MB | Lp 256KB
    __hip_bfloat16* qbf   = (__hip_bfloat16*)d_ws;
    __hip_bfloat16* kbf   = qbf + (size_t)4 * NPIX * 8;
    __hip_bfloat16* xbf   = kbf + (size_t)4 * NPIX * 8;
    __hip_bfloat16* Opart = xbf + (size_t)4 * NPIX * 64;
    float* Lp = (float*)(Opart + (size_t)2048 * 2048);

    prep_kernel<<<256, 512, 0, stream>>>(x, Wq, bq, Wk, bk, qbf, kbf, xbf);
    flash_part_kernel<<<2048, 256, 0, stream>>>(qbf, kbf, xbf, Opart, Lp);
    merge_kernel<<<256, 512, 0, stream>>>(Opart, Lp, Wv, bv, x, gamma, out);
}

// Round 7
// 115.009 us; speedup vs baseline: 1.0942x; 1.0942x over previous
//
#include <hip/hip_runtime.h>
#include <hip/hip_bf16.h>
#include <math.h>

#define NPIX 4096

typedef __attribute__((ext_vector_type(8))) short s8;   // 8 x bf16 (4 VGPRs)
typedef __attribute__((ext_vector_type(4))) float f4;   // 4 x f32

static __device__ __forceinline__ unsigned packbf2(float a, float b) {
    union { __hip_bfloat162 h; unsigned u; } x;
    x.h = __float22bfloat162_rn(make_float2(a, b));
    return x.u;
}
static __device__ __forceinline__ float2 unpackbf2(unsigned u) {
    float lo = __uint_as_float(u << 16);
    float hi = __uint_as_float(u & 0xffff0000u);
    return make_float2(lo, hi);
}

// ---------------------------------------------------------------------------
// Kernel 1: prep — q,k projections (bf16) + bf16 copy of x. (verified R5)
// q pre-scaled by log2(e) so flash uses exp2 (v_exp_f32) directly.
// ---------------------------------------------------------------------------
__global__ __launch_bounds__(512) void prep_kernel(
    const float* __restrict__ x,
    const float* __restrict__ Wq, const float* __restrict__ bq,
    const float* __restrict__ Wk, const float* __restrict__ bk,
    __hip_bfloat16* __restrict__ qbf, __hip_bfloat16* __restrict__ kbf,
    __hip_bfloat16* __restrict__ xbf)
{
    __shared__ float Xp[64][65];
    int t = threadIdx.x;
    int lane = t & 63;
    int grp  = t >> 6;               // 0..7, wave-uniform
    int b  = blockIdx.x >> 6;
    int n0 = (blockIdx.x & 63) << 6;

    const float* xb = x + ((size_t)b << 18);
    __hip_bfloat16* xbb = xbf + ((size_t)b << 18);
#pragma unroll
    for (int u = 0; u < 8; ++u) {
        int c = grp + u * 8;
        float v = xb[((size_t)c << 12) + n0 + lane];
        Xp[c][lane] = v;
        xbb[((size_t)c << 12) + n0 + lane] = __float2bfloat16(v);
    }
    __syncthreads();

    float qa = bq[grp], ka = bk[grp];
    const float* wq = Wq + grp * 64;   // wave-uniform base -> s_load
    const float* wk = Wk + grp * 64;
#pragma unroll
    for (int c = 0; c < 64; ++c) {
        float xv = Xp[c][lane];
        qa = fmaf(wq[c], xv, qa);
        ka = fmaf(wk[c], xv, ka);
    }
    qa *= 1.4426950408889634f;         // fold log2(e)
    int pix = b * NPIX + n0 + lane;
    qbf[(size_t)pix * 8 + grp] = __float2bfloat16(qa);
    kbf[(size_t)pix * 8 + grp] = __float2bfloat16(ka);
}

// ---------------------------------------------------------------------------
// Kernel 2: flash partial. R7: back to 64-i blocks (R6 lesson: per-block
// staging/barrier overhead is constant — halving the tile doubled total
// overhead). Occupancy fix instead: P·x splits waves over CHANNELS (16 c
// per wave, full 128-j tile) -> acc = 16 AGPRs; P goes through a SHARED
// PT buffer (score phase still j-striped per wave). ~68 regs total ->
// 4 waves/SIMD; LDS 34816 B -> 4 blocks/CU. Epilogue: c-ranges disjoint ->
// single parallel write, no serialization.
// Grid 1024 = sId(4, slowest) x b(4) x i-tile(64).
// ---------------------------------------------------------------------------
__global__ __launch_bounds__(256, 4) void flash_part_kernel(
    const __hip_bfloat16* __restrict__ qbf, const __hip_bfloat16* __restrict__ kbf,
    const __hip_bfloat16* __restrict__ xbf,
    __hip_bfloat16* __restrict__ Opart, float* __restrict__ Lp)
{
    // phase A: Xs [64][136] bf16 @0 (17408B) | PTs [64 i][136 j] bf16 @17408
    // phase B: Osh [64 i][68] f32 @0 (17408B) | Lsh [4][64] @17408
    __shared__ __align__(16) char pool[34816];
    unsigned short* Xs  = (unsigned short*)pool;
    unsigned short* PTs = (unsigned short*)(pool + 17408);

    int t = threadIdx.x;
    int w    = t >> 6;
    int lane = t & 63;
    int quad = lane >> 4;
    int c16  = lane & 15;

    int blk  = blockIdx.x;
    int sId  = blk >> 8;
    int rest = blk & 255;
    int b    = rest >> 6;
    int i0   = (rest & 63) << 6;
    int jbase = sId << 10;

    const s8 zero8 = {0, 0, 0, 0, 0, 0, 0, 0};
    const f4 zero4 = {0.f, 0.f, 0.f, 0.f};

    // Q B-frags (B[k=quad*8+dd][n=c16]); only quad0 holds real d (0..7)
    s8 qf[4];
#pragma unroll
    for (int it = 0; it < 4; ++it) {
        s8 qv = *(const s8*)(qbf + ((size_t)(b * NPIX + i0 + it * 16 + c16) << 3));
        qf[it] = (quad == 0) ? qv : zero8;
    }

    // acc[ic]: O[c = w*16 + quad*4 + reg][i = ic*16 + c16]
    f4 acc[4];
    float l[4] = {0.f, 0.f, 0.f, 0.f};
#pragma unroll
    for (int ic = 0; ic < 4; ++ic) acc[ic] = zero4;

    const __hip_bfloat16* kb = kbf + ((size_t)(b * NPIX) << 3);
    const unsigned short* xg = (const unsigned short*)xbf + ((size_t)b << 18);

    for (int tile = 0; tile < 8; ++tile) {
        int j0 = jbase + (tile << 7);

        __syncthreads();   // A: previous tile's Xs/PTs readers done
        {
            int c = t >> 2, seg = t & 3;
            const uint4* src = (const uint4*)(xg + ((size_t)c << 12) + j0 + seg * 32);
            uint4* dst = (uint4*)(Xs + c * 136 + seg * 32);
#pragma unroll
            for (int u = 0; u < 4; ++u) dst[u] = src[u];
        }
        // K frags for this wave's 32-j stripe (L2-hot)
        s8 kf0 = *(const s8*)(kb + ((size_t)(j0 + w * 32 + c16) << 3));
        s8 kf1 = *(const s8*)(kb + ((size_t)(j0 + w * 32 + 16 + c16) << 3));
        __syncthreads();   // B: Xs ready

        // scores + exp2, publish P^T to SHARED PTs[i][j] (i-major, stride 136)
#pragma unroll
        for (int it = 0; it < 4; ++it) {
            f4 s0 = __builtin_amdgcn_mfma_f32_16x16x32_bf16(kf0, qf[it], zero4, 0, 0, 0);
            f4 s1 = __builtin_amdgcn_mfma_f32_16x16x32_bf16(kf1, qf[it], zero4, 0, 0, 0);
            float e00 = exp2f(s0[0]), e01 = exp2f(s0[1]);
            float e02 = exp2f(s0[2]), e03 = exp2f(s0[3]);
            float e10 = exp2f(s1[0]), e11 = exp2f(s1[1]);
            float e12 = exp2f(s1[2]), e13 = exp2f(s1[3]);
            l[it] += ((e00 + e01) + (e02 + e03)) + ((e10 + e11) + (e12 + e13));
            int i = it * 16 + c16;
            uint2 pk0, pk1;
            pk0.x = packbf2(e00, e01); pk0.y = packbf2(e02, e03);
            pk1.x = packbf2(e10, e11); pk1.y = packbf2(e12, e13);
            // j = w*32 + jm*16 + quad*4 + r
            *(uint2*)(PTs + i * 136 + w * 32 + quad * 4) = pk0;        // jm=0
            *(uint2*)(PTs + i * 136 + w * 32 + 16 + quad * 4) = pk1;   // jm=1
        }
        __syncthreads();   // C: PTs ready (cross-wave)

        // P·x: wave w computes c in [16w,16w+16), all 64 i, full 128 j.
        // A = X[c][k-chunk] (m=c16 -> c=w*16+c16), B = P^T[k][i] (n=c16 -> i)
#pragma unroll
        for (int kc = 0; kc < 4; ++kc) {
            s8 xf = *(const s8*)(Xs + (w * 16 + c16) * 136 + kc * 32 + quad * 8);
#pragma unroll
            for (int ic = 0; ic < 4; ++ic) {
                s8 pf = *(const s8*)(PTs + (ic * 16 + c16) * 136 + kc * 32 + quad * 8);
                acc[ic] = __builtin_amdgcn_mfma_f32_16x16x32_bf16(xf, pf, acc[ic], 0, 0, 0);
            }
        }
    }

    // ---------------- epilogue ----------------
    float* Osh = (float*)pool;                 // [64 i][68]
    float* Lsh = (float*)(pool + 17408);       // [4][64]

#pragma unroll
    for (int it = 0; it < 4; ++it) {
        l[it] += __shfl_xor(l[it], 16);
        l[it] += __shfl_xor(l[it], 32);
    }
    __syncthreads();   // everyone done reading Xs/PTs
    if (quad == 0) {
#pragma unroll
        for (int it = 0; it < 4; ++it) Lsh[w * 64 + it * 16 + c16] = l[it];
    }
    // O write: disjoint c-ranges per wave -> single parallel pass
#pragma unroll
    for (int ic = 0; ic < 4; ++ic) {
        f4 v = acc[ic];
        *(float4*)(Osh + (ic * 16 + c16) * 68 + w * 16 + quad * 4) =
            make_float4(v[0], v[1], v[2], v[3]);
    }
    __syncthreads();

    if (t < 64)
        Lp[(size_t)blk * 64 + t] = Lsh[t] + Lsh[64 + t] + Lsh[128 + t] + Lsh[192 + t];

    // store partial O as bf16: thread t -> row i = t>>2, cols [(t&3)*16, +16)
    {
        int i = t >> 2, c0 = (t & 3) << 4;
        const float* src = Osh + i * 68 + c0;
        uint4 lo, hi;
        lo.x = packbf2(src[0], src[1]);   lo.y = packbf2(src[2], src[3]);
        lo.z = packbf2(src[4], src[5]);   lo.w = packbf2(src[6], src[7]);
        hi.x = packbf2(src[8], src[9]);   hi.y = packbf2(src[10], src[11]);
        hi.z = packbf2(src[12], src[13]); hi.w = packbf2(src[14], src[15]);
        uint4* dst = (uint4*)(Opart + (size_t)blk * 4096 + i * 64 + c0);
        dst[0] = lo; dst[1] = hi;
    }
}

// ---------------------------------------------------------------------------
// Kernel 3: merge 4 partials (plain sums) + Wv projection + bias + residual.
// (verified R4/R5 version; flash blocks are 64-i, sId stride 256)
// ---------------------------------------------------------------------------
__global__ __launch_bounds__(512) void merge_kernel(
    const __hip_bfloat16* __restrict__ Opart, const float* __restrict__ Lp,
    const float* __restrict__ Wv, const float* __restrict__ bv,
    const float* __restrict__ x, const float* __restrict__ gamma,
    float* __restrict__ out)
{
    __shared__ float Osh[64 * 68];
    __shared__ float Wvs[4096];
    __shared__ float LinvS[64];
    __shared__ float bvs[64];

    int t = threadIdx.x;
    int b  = blockIdx.x >> 6;
    int i0 = (blockIdx.x & 63) << 6;

    if (t < 64) {
        int i = t;
        float lt = Lp[(size_t)(0 * 256 + blockIdx.x) * 64 + i]
                 + Lp[(size_t)(1 * 256 + blockIdx.x) * 64 + i]
                 + Lp[(size_t)(2 * 256 + blockIdx.x) * 64 + i]
                 + Lp[(size_t)(3 * 256 + blockIdx.x) * 64 + i];
        LinvS[i] = 1.0f / lt;
        bvs[i] = bv[i];
    }
    {
        const float4* wsrc = (const float4*)Wv;
        float4* wdst = (float4*)Wvs;
        wdst[t] = wsrc[t];
        wdst[t + 512] = wsrc[t + 512];
    }
    __syncthreads();

    {
        int i = t >> 3, c0 = (t & 7) << 3;
        float o[8];
#pragma unroll
        for (int k = 0; k < 8; ++k) o[k] = 0.f;
#pragma unroll
        for (int sId = 0; sId < 4; ++sId) {
            size_t base = (size_t)(sId * 256 + blockIdx.x) * 4096 + i * 64 + c0;
            uint4 pk = *(const uint4*)(Opart + base);
            float2 e0 = unpackbf2(pk.x), e1 = unpackbf2(pk.y);
            float2 e2 = unpackbf2(pk.z), e3 = unpackbf2(pk.w);
            o[0] += e0.x; o[1] += e0.y; o[2] += e1.x; o[3] += e1.y;
            o[4] += e2.x; o[5] += e2.y; o[6] += e3.x; o[7] += e3.y;
        }
        float* dst = Osh + i * 68 + c0;
        *(float4*)(dst + 0) = make_float4(o[0], o[1], o[2], o[3]);
        *(float4*)(dst + 4) = make_float4(o[4], o[5], o[6], o[7]);
    }
    __syncthreads();

    {
        int i  = t & 63;
        int cg = t >> 6;
        float inv = LinvS[i];
        float res[8];
#pragma unroll
        for (int k = 0; k < 8; ++k) res[k] = 0.f;
#pragma unroll 4
        for (int cb = 0; cb < 16; ++cb) {
            float4 o = *(const float4*)(Osh + i * 68 + cb * 4);
#pragma unroll
            for (int k = 0; k < 8; ++k) {
                float4 wv4 = *(const float4*)(Wvs + (cg * 8 + k) * 64 + cb * 4);
                res[k] = fmaf(wv4.x, o.x, fmaf(wv4.y, o.y, fmaf(wv4.z, o.z, fmaf(wv4.w, o.w, res[k]))));
            }
        }
        float g = gamma[0];
        const float* xr = x + ((size_t)b << 18) + i0;
        float* outp = out + ((size_t)b << 18) + i0;
#pragma unroll
        for (int k = 0; k < 8; ++k) {
            int c = cg * 8 + k;
            float attn = fmaf(res[k], inv, bvs[c]);
            size_t off = ((size_t)c << 12) + i;
            outp[off] = fmaf(g, attn, xr[off]);
        }
    }
}

extern "C" void kernel_launch(void* const* d_in, const int* in_sizes, int n_in,
                              void* d_out, int out_size, void* d_ws, size_t ws_size,
                              hipStream_t stream) {
    const float* x     = (const float*)d_in[0];
    const float* Wq    = (const float*)d_in[1];
    const float* bq    = (const float*)d_in[2];
    const float* Wk    = (const float*)d_in[3];
    const float* bk    = (const float*)d_in[4];
    const float* Wv    = (const float*)d_in[5];
    const float* bv    = (const float*)d_in[6];
    const float* gamma = (const float*)d_in[7];
    float* out = (float*)d_out;

    // ws: qbf 256KB | kbf 256KB | xbf 2MB | Opart 8MB | Lp 256KB
    __hip_bfloat16* qbf   = (__hip_bfloat16*)d_ws;
    __hip_bfloat16* kbf   = qbf + (size_t)4 * NPIX * 8;
    __hip_bfloat16* xbf   = kbf + (size_t)4 * NPIX * 8;
    __hip_bfloat16* Opart = xbf + (size_t)4 * NPIX * 64;
    float* Lp = (float*)(Opart + (size_t)1024 * 4096);

    prep_kernel<<<256, 512, 0, stream>>>(x, Wq, bq, Wk, bk, qbf, kbf, xbf);
    flash_part_kernel<<<1024, 256, 0, stream>>>(qbf, kbf, xbf, Opart, Lp);
    merge_kernel<<<256, 512, 0, stream>>>(Opart, Lp, Wv, bv, x, gamma, out);
}

// Round 8
// 111.013 us; speedup vs baseline: 1.1336x; 1.0360x over previous
//
#include <hip/hip_runtime.h>
#include <hip/hip_bf16.h>
#include <math.h>

#define NPIX 4096

typedef __attribute__((ext_vector_type(8))) short s8;    // 8 x bf16 (4 VGPRs)
typedef __attribute__((ext_vector_type(4))) float f4;    // 4 x f32
typedef __attribute__((ext_vector_type(16))) float f16v; // 16 x f32 (32x32 acc)

static __device__ __forceinline__ unsigned packbf2(float a, float b) {
    union { __hip_bfloat162 h; unsigned u; } x;
    x.h = __float22bfloat162_rn(make_float2(a, b));
    return x.u;
}
static __device__ __forceinline__ float2 unpackbf2(unsigned u) {
    float lo = __uint_as_float(u << 16);
    float hi = __uint_as_float(u & 0xffff0000u);
    return make_float2(lo, hi);
}

// ---------------------------------------------------------------------------
// Kernel 1: prep — q,k projections (bf16) + bf16 copy of x. (verified R5)
// q pre-scaled by log2(e) so flash uses exp2 (v_exp_f32) directly.
// ---------------------------------------------------------------------------
__global__ __launch_bounds__(512) void prep_kernel(
    const float* __restrict__ x,
    const float* __restrict__ Wq, const float* __restrict__ bq,
    const float* __restrict__ Wk, const float* __restrict__ bk,
    __hip_bfloat16* __restrict__ qbf, __hip_bfloat16* __restrict__ kbf,
    __hip_bfloat16* __restrict__ xbf)
{
    __shared__ float Xp[64][65];
    int t = threadIdx.x;
    int lane = t & 63;
    int grp  = t >> 6;               // 0..7, wave-uniform
    int b  = blockIdx.x >> 6;
    int n0 = (blockIdx.x & 63) << 6;

    const float* xb = x + ((size_t)b << 18);
    __hip_bfloat16* xbb = xbf + ((size_t)b << 18);
#pragma unroll
    for (int u = 0; u < 8; ++u) {
        int c = grp + u * 8;
        float v = xb[((size_t)c << 12) + n0 + lane];
        Xp[c][lane] = v;
        xbb[((size_t)c << 12) + n0 + lane] = __float2bfloat16(v);
    }
    __syncthreads();

    float qa = bq[grp], ka = bk[grp];
    const float* wq = Wq + grp * 64;   // wave-uniform base -> s_load
    const float* wk = Wk + grp * 64;
#pragma unroll
    for (int c = 0; c < 64; ++c) {
        float xv = Xp[c][lane];
        qa = fmaf(wq[c], xv, qa);
        ka = fmaf(wk[c], xv, ka);
    }
    qa *= 1.4426950408889634f;         // fold log2(e)
    int pix = b * NPIX + n0 + lane;
    qbf[(size_t)pix * 8 + grp] = __float2bfloat16(qa);
    kbf[(size_t)pix * 8 + grp] = __float2bfloat16(ka);
}

// ---------------------------------------------------------------------------
// Kernel 2: flash partial. R8 changes vs R7 (same grid 1024, same tiling):
//  (a) 2 barriers/tile (was 3): scores depend only on global kf/qf, so
//      stage-writes + scores + PT-publish share one phase; stage-load
//      latency hides under score MFMA/exp work.
//  (b) P·x uses mfma_f32_32x32x16_bf16: per wave 8 MFMA + 16 b128 LDS reads
//      (was 16 MFMA + 20 reads). A[m=lane&31→c][k=(lane>>5)*8+r→j] and
//      B[k][n=lane&31→i] read the natural-order Xs/PTs — no layout change.
//      Wave w owns c-half (w&1) x i-half (w>>1); acc 16 AGPRs.
//      C/D (m74/m101): col=lane&31→i, row=(reg&3)+8*(reg>>2)+4*(lane>>5)→c.
// ---------------------------------------------------------------------------
__global__ __launch_bounds__(256, 4) void flash_part_kernel(
    const __hip_bfloat16* __restrict__ qbf, const __hip_bfloat16* __restrict__ kbf,
    const __hip_bfloat16* __restrict__ xbf,
    __hip_bfloat16* __restrict__ Opart, float* __restrict__ Lp)
{
    // phase A: Xs [64][136] bf16 @0 (17408B) | PTs [64 i][136 j] bf16 @17408
    // phase B: Osh [64 i][68] f32 @0 (17408B) | Lsh [4][64] @17408
    __shared__ __align__(16) char pool[34816];
    unsigned short* Xs  = (unsigned short*)pool;
    unsigned short* PTs = (unsigned short*)(pool + 17408);

    int t = threadIdx.x;
    int w    = t >> 6;
    int lane = t & 63;
    int quad = lane >> 4;
    int c16  = lane & 15;
    int l32  = lane & 31;
    int lh   = lane >> 5;            // half-wave index (k-half in 32x32 frags)
    int chalf = w & 1;               // P·x: c in [32*chalf, +32)
    int ihalf = w >> 1;              // P·x: i in [32*ihalf, +32)

    int blk  = blockIdx.x;
    int sId  = blk >> 8;
    int rest = blk & 255;
    int b    = rest >> 6;
    int i0   = (rest & 63) << 6;
    int jbase = sId << 10;

    const s8 zero8 = {0, 0, 0, 0, 0, 0, 0, 0};
    const f4 zero4 = {0.f, 0.f, 0.f, 0.f};

    // Q B-frags (B[k=quad*8+dd][n=c16]); only quad0 holds real d (0..7)
    s8 qf[4];
#pragma unroll
    for (int it = 0; it < 4; ++it) {
        s8 qv = *(const s8*)(qbf + ((size_t)(b * NPIX + i0 + it * 16 + c16) << 3));
        qf[it] = (quad == 0) ? qv : zero8;
    }

    f16v acc = {0.f};
#pragma unroll
    for (int r = 0; r < 16; ++r) acc[r] = 0.f;
    float l[4] = {0.f, 0.f, 0.f, 0.f};

    const __hip_bfloat16* kb = kbf + ((size_t)(b * NPIX) << 3);
    const unsigned short* xg = (const unsigned short*)xbf + ((size_t)b << 18);

    for (int tile = 0; tile < 8; ++tile) {
        int j0 = jbase + (tile << 7);

        __syncthreads();   // A: previous tile's P·x readers done with Xs/PTs

        // issue stage loads + K loads (latency overlaps scores below)
        int c = t >> 2, seg = t & 3;
        const uint4* src = (const uint4*)(xg + ((size_t)c << 12) + j0 + seg * 32);
        uint4 sv0 = src[0], sv1 = src[1], sv2 = src[2], sv3 = src[3];
        s8 kf0 = *(const s8*)(kb + ((size_t)(j0 + w * 32 + c16) << 3));
        s8 kf1 = *(const s8*)(kb + ((size_t)(j0 + w * 32 + 16 + c16) << 3));

        // stage-write Xs (waits only sv*)
        {
            uint4* dst = (uint4*)(Xs + c * 136 + seg * 32);
            dst[0] = sv0; dst[1] = sv1; dst[2] = sv2; dst[3] = sv3;
        }

        // scores + exp2, publish P^T to shared PTs[i][j] (depends on kf/qf only)
#pragma unroll
        for (int it = 0; it < 4; ++it) {
            f4 s0 = __builtin_amdgcn_mfma_f32_16x16x32_bf16(kf0, qf[it], zero4, 0, 0, 0);
            f4 s1 = __builtin_amdgcn_mfma_f32_16x16x32_bf16(kf1, qf[it], zero4, 0, 0, 0);
            float e00 = exp2f(s0[0]), e01 = exp2f(s0[1]);
            float e02 = exp2f(s0[2]), e03 = exp2f(s0[3]);
            float e10 = exp2f(s1[0]), e11 = exp2f(s1[1]);
            float e12 = exp2f(s1[2]), e13 = exp2f(s1[3]);
            l[it] += ((e00 + e01) + (e02 + e03)) + ((e10 + e11) + (e12 + e13));
            int i = it * 16 + c16;
            uint2 pk0, pk1;
            pk0.x = packbf2(e00, e01); pk0.y = packbf2(e02, e03);
            pk1.x = packbf2(e10, e11); pk1.y = packbf2(e12, e13);
            // j = w*32 + jm*16 + quad*4 + r
            *(uint2*)(PTs + i * 136 + w * 32 + quad * 4) = pk0;        // jm=0
            *(uint2*)(PTs + i * 136 + w * 32 + 16 + quad * 4) = pk1;   // jm=1
        }
        __syncthreads();   // B: Xs + PTs ready

        // P·x, 32x32x16: 8 k-chunks of 16 j
#pragma unroll
        for (int q = 0; q < 8; ++q) {
            s8 xf = *(const s8*)(Xs  + (chalf * 32 + l32) * 136 + q * 16 + lh * 8);
            s8 pf = *(const s8*)(PTs + (ihalf * 32 + l32) * 136 + q * 16 + lh * 8);
            acc = __builtin_amdgcn_mfma_f32_32x32x16_bf16(xf, pf, acc, 0, 0, 0);
        }
    }

    // ---------------- epilogue ----------------
    float* Osh = (float*)pool;                 // [64 i][68]
    float* Lsh = (float*)(pool + 17408);       // [4][64]

#pragma unroll
    for (int it = 0; it < 4; ++it) {
        l[it] += __shfl_xor(l[it], 16);
        l[it] += __shfl_xor(l[it], 32);
    }
    __syncthreads();   // everyone done reading Xs/PTs
    if (quad == 0) {
#pragma unroll
        for (int it = 0; it < 4; ++it) Lsh[w * 64 + it * 16 + c16] = l[it];
    }
    // O write: wave w owns disjoint (c-half, i-half) -> parallel scalar writes
    {
        int i = ihalf * 32 + l32;
#pragma unroll
        for (int r = 0; r < 16; ++r) {
            int cc = chalf * 32 + (r & 3) + 8 * (r >> 2) + 4 * lh;
            Osh[i * 68 + cc] = acc[r];
        }
    }
    __syncthreads();

    if (t < 64)
        Lp[(size_t)blk * 64 + t] = Lsh[t] + Lsh[64 + t] + Lsh[128 + t] + Lsh[192 + t];

    // store partial O as bf16: thread t -> row i = t>>2, cols [(t&3)*16, +16)
    {
        int i = t >> 2, c0 = (t & 3) << 4;
        const float* src = Osh + i * 68 + c0;
        uint4 lo, hi;
        lo.x = packbf2(src[0], src[1]);   lo.y = packbf2(src[2], src[3]);
        lo.z = packbf2(src[4], src[5]);   lo.w = packbf2(src[6], src[7]);
        hi.x = packbf2(src[8], src[9]);   hi.y = packbf2(src[10], src[11]);
        hi.z = packbf2(src[12], src[13]); hi.w = packbf2(src[14], src[15]);
        uint4* dst = (uint4*)(Opart + (size_t)blk * 4096 + i * 64 + c0);
        dst[0] = lo; dst[1] = hi;
    }
}

// ---------------------------------------------------------------------------
// Kernel 3: merge 4 partials (plain sums) + Wv projection + bias + residual.
// (verified R4/R5/R7; flash blocks are 64-i, sId stride 256)
// ---------------------------------------------------------------------------
__global__ __launch_bounds__(512) void merge_kernel(
    const __hip_bfloat16* __restrict__ Opart, const float* __restrict__ Lp,
    const float* __restrict__ Wv, const float* __restrict__ bv,
    const float* __restrict__ x, const float* __restrict__ gamma,
    float* __restrict__ out)
{
    __shared__ float Osh[64 * 68];
    __shared__ float Wvs[4096];
    __shared__ float LinvS[64];
    __shared__ float bvs[64];

    int t = threadIdx.x;
    int b  = blockIdx.x >> 6;
    int i0 = (blockIdx.x & 63) << 6;

    if (t < 64) {
        int i = t;
        float lt = Lp[(size_t)(0 * 256 + blockIdx.x) * 64 + i]
                 + Lp[(size_t)(1 * 256 + blockIdx.x) * 64 + i]
                 + Lp[(size_t)(2 * 256 + blockIdx.x) * 64 + i]
                 + Lp[(size_t)(3 * 256 + blockIdx.x) * 64 + i];
        LinvS[i] = 1.0f / lt;
        bvs[i] = bv[i];
    }
    {
        const float4* wsrc = (const float4*)Wv;
        float4* wdst = (float4*)Wvs;
        wdst[t] = wsrc[t];
        wdst[t + 512] = wsrc[t + 512];
    }
    __syncthreads();

    {
        int i = t >> 3, c0 = (t & 7) << 3;
        float o[8];
#pragma unroll
        for (int k = 0; k < 8; ++k) o[k] = 0.f;
#pragma unroll
        for (int sId = 0; sId < 4; ++sId) {
            size_t base = (size_t)(sId * 256 + blockIdx.x) * 4096 + i * 64 + c0;
            uint4 pk = *(const uint4*)(Opart + base);
            float2 e0 = unpackbf2(pk.x), e1 = unpackbf2(pk.y);
            float2 e2 = unpackbf2(pk.z), e3 = unpackbf2(pk.w);
            o[0] += e0.x; o[1] += e0.y; o[2] += e1.x; o[3] += e1.y;
            o[4] += e2.x; o[5] += e2.y; o[6] += e3.x; o[7] += e3.y;
        }
        float* dst = Osh + i * 68 + c0;
        *(float4*)(dst + 0) = make_float4(o[0], o[1], o[2], o[3]);
        *(float4*)(dst + 4) = make_float4(o[4], o[5], o[6], o[7]);
    }
    __syncthreads();

    {
        int i  = t & 63;
        int cg = t >> 6;
        float inv = LinvS[i];
        float res[8];
#pragma unroll
        for (int k = 0; k < 8; ++k) res[k] = 0.f;
#pragma unroll 4
        for (int cb = 0; cb < 16; ++cb) {
            float4 o = *(const float4*)(Osh + i * 68 + cb * 4);
#pragma unroll
            for (int k = 0; k < 8; ++k) {
                float4 wv4 = *(const float4*)(Wvs + (cg * 8 + k) * 64 + cb * 4);
                res[k] = fmaf(wv4.x, o.x, fmaf(wv4.y, o.y, fmaf(wv4.z, o.z, fmaf(wv4.w, o.w, res[k]))));
            }
        }
        float g = gamma[0];
        const float* xr = x + ((size_t)b << 18) + i0;
        float* outp = out + ((size_t)b << 18) + i0;
#pragma unroll
        for (int k = 0; k < 8; ++k) {
            int c = cg * 8 + k;
            float attn = fmaf(res[k], inv, bvs[c]);
            size_t off = ((size_t)c << 12) + i;
            outp[off] = fmaf(g, attn, xr[off]);
        }
    }
}

extern "C" void kernel_launch(void* const* d_in, const int* in_sizes, int n_in,
                              void* d_out, int out_size, void* d_ws, size_t ws_size,
                              hipStream_t stream) {
    const float* x     = (const float*)d_in[0];
    const float* Wq    = (const float*)d_in[1];
    const float* bq    = (const float*)d_in[2];
    const float* Wk    = (const float*)d_in[3];
    const float* bk    = (const float*)d_in[4];
    const float* Wv    = (const float*)d_in[5];
    const float* bv    = (const float*)d_in[6];
    const float* gamma = (const float*)d_in[7];
    float* out = (float*)d_out;

    // ws: qbf 256KB | kbf 256KB | xbf 2MB | Opart 8MB | Lp 256KB
    __hip_bfloat16* qbf   = (__hip_bfloat16*)d_ws;
    __hip_bfloat16* kbf   = qbf + (size_t)4 * NPIX * 8;
    __hip_bfloat16* xbf   = kbf + (size_t)4 * NPIX * 8;
    __hip_bfloat16* Opart = xbf + (size_t)4 * NPIX * 64;
    float* Lp = (float*)(Opart + (size_t)1024 * 4096);

    prep_kernel<<<256, 512, 0, stream>>>(x, Wq, bq, Wk, bk, qbf, kbf, xbf);
    flash_part_kernel<<<1024, 256, 0, stream>>>(qbf, kbf, xbf, Opart, Lp);
    merge_kernel<<<256, 512, 0, stream>>>(Opart, Lp, Wv, bv, x, gamma, out);
}

// Round 9
// 110.688 us; speedup vs baseline: 1.1369x; 1.0029x over previous
//
#include <hip/hip_runtime.h>
#include <hip/hip_bf16.h>
#include <math.h>

#define NPIX 4096

typedef __attribute__((ext_vector_type(8))) short s8;    // 8 x bf16 (4 VGPRs)
typedef __attribute__((ext_vector_type(4))) float f4;    // 4 x f32
typedef __attribute__((ext_vector_type(16))) float f16v; // 16 x f32 (32x32 acc)

static __device__ __forceinline__ unsigned packbf2(float a, float b) {
    union { __hip_bfloat162 h; unsigned u; } x;
    x.h = __float22bfloat162_rn(make_float2(a, b));
    return x.u;
}
static __device__ __forceinline__ float2 unpackbf2(unsigned u) {
    float lo = __uint_as_float(u << 16);
    float hi = __uint_as_float(u & 0xffff0000u);
    return make_float2(lo, hi);
}

// ---------------------------------------------------------------------------
// Kernel 1: prep — q,k projections (bf16) + bf16 copy of x. (verified R5)
// q pre-scaled by log2(e) so flash uses exp2 (v_exp_f32) directly.
// ---------------------------------------------------------------------------
__global__ __launch_bounds__(512) void prep_kernel(
    const float* __restrict__ x,
    const float* __restrict__ Wq, const float* __restrict__ bq,
    const float* __restrict__ Wk, const float* __restrict__ bk,
    __hip_bfloat16* __restrict__ qbf, __hip_bfloat16* __restrict__ kbf,
    __hip_bfloat16* __restrict__ xbf)
{
    __shared__ float Xp[64][65];
    int t = threadIdx.x;
    int lane = t & 63;
    int grp  = t >> 6;               // 0..7, wave-uniform
    int b  = blockIdx.x >> 6;
    int n0 = (blockIdx.x & 63) << 6;

    const float* xb = x + ((size_t)b << 18);
    __hip_bfloat16* xbb = xbf + ((size_t)b << 18);
#pragma unroll
    for (int u = 0; u < 8; ++u) {
        int c = grp + u * 8;
        float v = xb[((size_t)c << 12) + n0 + lane];
        Xp[c][lane] = v;
        xbb[((size_t)c << 12) + n0 + lane] = __float2bfloat16(v);
    }
    __syncthreads();

    float qa = bq[grp], ka = bk[grp];
    const float* wq = Wq + grp * 64;   // wave-uniform base -> s_load
    const float* wk = Wk + grp * 64;
#pragma unroll
    for (int c = 0; c < 64; ++c) {
        float xv = Xp[c][lane];
        qa = fmaf(wq[c], xv, qa);
        ka = fmaf(wk[c], xv, ka);
    }
    qa *= 1.4426950408889634f;         // fold log2(e)
    int pix = b * NPIX + n0 + lane;
    qbf[(size_t)pix * 8 + grp] = __float2bfloat16(qa);
    kbf[(size_t)pix * 8 + grp] = __float2bfloat16(ka);
}

// ---------------------------------------------------------------------------
// Kernel 2: flash partial. R9 vs R8 (same grid/tiling/LDS/merge interface):
//  (a) scores via mfma_f32_32x32x16_bf16: 2 MFMA/wave-tile (was 8), kf load
//      16B (was 32B). Same A/B frag convention R8 verified for P·x:
//      A[m=lane&31][k=lh*8+r], B[k=lh*8+r][n=lane&31]; d>=8 killed by
//      zeroed B (qf) lh=1 half. C/D: col=lane&31->i, row=(r&3)+8(r>>2)+4lh->j.
//  (b) j-tile visit order staggered per sId (sum-only softmax -> order-free):
//      co-resident blocks (blk, +256, +512, +768) start at different tiles,
//      de-aligning their LDS/barrier bursts.
// ---------------------------------------------------------------------------
__global__ __launch_bounds__(256, 4) void flash_part_kernel(
    const __hip_bfloat16* __restrict__ qbf, const __hip_bfloat16* __restrict__ kbf,
    const __hip_bfloat16* __restrict__ xbf,
    __hip_bfloat16* __restrict__ Opart, float* __restrict__ Lp)
{
    // phase A: Xs [64][136] bf16 @0 (17408B) | PTs [64 i][136 j] bf16 @17408
    // phase B: Osh [64 i][68] f32 @0 (17408B) | Lsh [4][64] @17408
    __shared__ __align__(16) char pool[34816];
    unsigned short* Xs  = (unsigned short*)pool;
    unsigned short* PTs = (unsigned short*)(pool + 17408);

    int t = threadIdx.x;
    int w    = t >> 6;
    int lane = t & 63;
    int l32  = lane & 31;
    int lh   = lane >> 5;            // k-half index in 32x32 frags
    int chalf = w & 1;               // P·x: c in [32*chalf, +32)
    int ihalf = w >> 1;              // P·x: i in [32*ihalf, +32)

    int blk  = blockIdx.x;
    int sId  = blk >> 8;
    int rest = blk & 255;
    int b    = rest >> 6;
    int i0   = (rest & 63) << 6;
    int jbase = sId << 10;
    int phase = (sId << 1) & 7;      // stagger start tile per sId

    const s8 zero8 = {0, 0, 0, 0, 0, 0, 0, 0};

    // Q B-frags: B[k=lh*8+r][n=l32 -> i=it32*32+l32]; lh=1 half zeroed (d<8)
    s8 qf[2];
#pragma unroll
    for (int it32 = 0; it32 < 2; ++it32) {
        s8 qv = *(const s8*)(qbf + ((size_t)(b * NPIX + i0 + it32 * 32 + l32) << 3));
        qf[it32] = (lh == 0) ? qv : zero8;
    }

    f16v acc;
#pragma unroll
    for (int r = 0; r < 16; ++r) acc[r] = 0.f;
    f16v zero16;
#pragma unroll
    for (int r = 0; r < 16; ++r) zero16[r] = 0.f;
    float l[2] = {0.f, 0.f};

    const __hip_bfloat16* kb = kbf + ((size_t)(b * NPIX) << 3);
    const unsigned short* xg = (const unsigned short*)xbf + ((size_t)b << 18);

    for (int tt = 0; tt < 8; ++tt) {
        int tile = (tt + phase) & 7;
        int j0 = jbase + (tile << 7);

        __syncthreads();   // A: previous tile's P·x readers done with Xs/PTs

        // stage loads + K load (latency overlaps scores below)
        int c = t >> 2, seg = t & 3;
        const uint4* src = (const uint4*)(xg + ((size_t)c << 12) + j0 + seg * 32);
        uint4 sv0 = src[0], sv1 = src[1], sv2 = src[2], sv3 = src[3];
        // A-frag: K[j = j0 + w*32 + l32][d 0..7]; lh=1 lanes load same row
        // (finite values; d>=8 products killed by zeroed qf half)
        s8 kf = *(const s8*)(kb + ((size_t)(j0 + w * 32 + l32) << 3));

        {
            uint4* dst = (uint4*)(Xs + c * 136 + seg * 32);
            dst[0] = sv0; dst[1] = sv1; dst[2] = sv2; dst[3] = sv3;
        }

        // scores S^T[j][i] (32x32 per MFMA) + exp2 + publish to PTs[i][j]
#pragma unroll
        for (int it32 = 0; it32 < 2; ++it32) {
            f16v sv = __builtin_amdgcn_mfma_f32_32x32x16_bf16(kf, qf[it32], zero16, 0, 0, 0);
            int i = it32 * 32 + l32;
            float ls = 0.f;
#pragma unroll
            for (int g = 0; g < 4; ++g) {
                float e0 = exp2f(sv[4 * g + 0]);
                float e1 = exp2f(sv[4 * g + 1]);
                float e2 = exp2f(sv[4 * g + 2]);
                float e3 = exp2f(sv[4 * g + 3]);
                ls += (e0 + e1) + (e2 + e3);
                uint2 pk;
                pk.x = packbf2(e0, e1); pk.y = packbf2(e2, e3);
                // j = w*32 + 8g + 4lh + {0..3}
                *(uint2*)(PTs + i * 136 + w * 32 + 8 * g + 4 * lh) = pk;
            }
            l[it32] += ls;
        }
        __syncthreads();   // B: Xs + PTs ready

        // P·x, 32x32x16: 8 k-chunks of 16 j
#pragma unroll
        for (int q = 0; q < 8; ++q) {
            s8 xf = *(const s8*)(Xs  + (chalf * 32 + l32) * 136 + q * 16 + lh * 8);
            s8 pf = *(const s8*)(PTs + (ihalf * 32 + l32) * 136 + q * 16 + lh * 8);
            acc = __builtin_amdgcn_mfma_f32_32x32x16_bf16(xf, pf, acc, 0, 0, 0);
        }
    }

    // ---------------- epilogue ----------------
    float* Osh = (float*)pool;                 // [64 i][68]
    float* Lsh = (float*)(pool + 17408);       // [4][64]

    // each lane covers 16 of its stripe's 32 j per i; partner is lane^32
#pragma unroll
    for (int it32 = 0; it32 < 2; ++it32)
        l[it32] += __shfl_xor(l[it32], 32);

    __syncthreads();   // everyone done reading Xs/PTs
    if (lh == 0) {
#pragma unroll
        for (int it32 = 0; it32 < 2; ++it32)
            Lsh[w * 64 + it32 * 32 + l32] = l[it32];
    }
    // O write: wave w owns disjoint (c-half, i-half) -> parallel scalar writes
    {
        int i = ihalf * 32 + l32;
#pragma unroll
        for (int r = 0; r < 16; ++r) {
            int cc = chalf * 32 + (r & 3) + 8 * (r >> 2) + 4 * lh;
            Osh[i * 68 + cc] = acc[r];
        }
    }
    __syncthreads();

    if (t < 64)
        Lp[(size_t)blk * 64 + t] = Lsh[t] + Lsh[64 + t] + Lsh[128 + t] + Lsh[192 + t];

    // store partial O as bf16: thread t -> row i = t>>2, cols [(t&3)*16, +16)
    {
        int i = t >> 2, c0 = (t & 3) << 4;
        const float* src = Osh + i * 68 + c0;
        uint4 lo, hi;
        lo.x = packbf2(src[0], src[1]);   lo.y = packbf2(src[2], src[3]);
        lo.z = packbf2(src[4], src[5]);   lo.w = packbf2(src[6], src[7]);
        hi.x = packbf2(src[8], src[9]);   hi.y = packbf2(src[10], src[11]);
        hi.z = packbf2(src[12], src[13]); hi.w = packbf2(src[14], src[15]);
        uint4* dst = (uint4*)(Opart + (size_t)blk * 4096 + i * 64 + c0);
        dst[0] = lo; dst[1] = hi;
    }
}

// ---------------------------------------------------------------------------
// Kernel 3: merge 4 partials (plain sums) + Wv projection + bias + residual.
// (verified R4/R5/R7; flash blocks are 64-i, sId stride 256)
// ---------------------------------------------------------------------------
__global__ __launch_bounds__(512) void merge_kernel(
    const __hip_bfloat16* __restrict__ Opart, const float* __restrict__ Lp,
    const float* __restrict__ Wv, const float* __restrict__ bv,
    const float* __restrict__ x, const float* __restrict__ gamma,
    float* __restrict__ out)
{
    __shared__ float Osh[64 * 68];
    __shared__ float Wvs[4096];
    __shared__ float LinvS[64];
    __shared__ float bvs[64];

    int t = threadIdx.x;
    int b  = blockIdx.x >> 6;
    int i0 = (blockIdx.x & 63) << 6;

    if (t < 64) {
        int i = t;
        float lt = Lp[(size_t)(0 * 256 + blockIdx.x) * 64 + i]
                 + Lp[(size_t)(1 * 256 + blockIdx.x) * 64 + i]
                 + Lp[(size_t)(2 * 256 + blockIdx.x) * 64 + i]
                 + Lp[(size_t)(3 * 256 + blockIdx.x) * 64 + i];
        LinvS[i] = 1.0f / lt;
        bvs[i] = bv[i];
    }
    {
        const float4* wsrc = (const float4*)Wv;
        float4* wdst = (float4*)Wvs;
        wdst[t] = wsrc[t];
        wdst[t + 512] = wsrc[t + 512];
    }
    __syncthreads();

    {
        int i = t >> 3, c0 = (t & 7) << 3;
        float o[8];
#pragma unroll
        for (int k = 0; k < 8; ++k) o[k] = 0.f;
#pragma unroll
        for (int sId = 0; sId < 4; ++sId) {
            size_t base = (size_t)(sId * 256 + blockIdx.x) * 4096 + i * 64 + c0;
            uint4 pk = *(const uint4*)(Opart + base);
            float2 e0 = unpackbf2(pk.x), e1 = unpackbf2(pk.y);
            float2 e2 = unpackbf2(pk.z), e3 = unpackbf2(pk.w);
            o[0] += e0.x; o[1] += e0.y; o[2] += e1.x; o[3] += e1.y;
            o[4] += e2.x; o[5] += e2.y; o[6] += e3.x; o[7] += e3.y;
        }
        float* dst = Osh + i * 68 + c0;
        *(float4*)(dst + 0) = make_float4(o[0], o[1], o[2], o[3]);
        *(float4*)(dst + 4) = make_float4(o[4], o[5], o[6], o[7]);
    }
    __syncthreads();

    {
        int i  = t & 63;
        int cg = t >> 6;
        float inv = LinvS[i];
        float res[8];
#pragma unroll
        for (int k = 0; k < 8; ++k) res[k] = 0.f;
#pragma unroll 4
        for (int cb = 0; cb < 16; ++cb) {
            float4 o = *(const float4*)(Osh + i * 68 + cb * 4);
#pragma unroll
            for (int k = 0; k < 8; ++k) {
                float4 wv4 = *(const float4*)(Wvs + (cg * 8 + k) * 64 + cb * 4);
                res[k] = fmaf(wv4.x, o.x, fmaf(wv4.y, o.y, fmaf(wv4.z, o.z, fmaf(wv4.w, o.w, res[k]))));
            }
        }
        float g = gamma[0];
        const float* xr = x + ((size_t)b << 18) + i0;
        float* outp = out + ((size_t)b << 18) + i0;
#pragma unroll
        for (int k = 0; k < 8; ++k) {
            int c = cg * 8 + k;
            float attn = fmaf(res[k], inv, bvs[c]);
            size_t off = ((size_t)c << 12) + i;
            outp[off] = fmaf(g, attn, xr[off]);
        }
    }
}

extern "C" void kernel_launch(void* const* d_in, const int* in_sizes, int n_in,
                              void* d_out, int out_size, void* d_ws, size_t ws_size,
                              hipStream_t stream) {
    const float* x     = (const float*)d_in[0];
    const float* Wq    = (const float*)d_in[1];
    const float* bq    = (const float*)d_in[2];
    const float* Wk    = (const float*)d_in[3];
    const float* bk    = (const float*)d_in[4];
    const float* Wv    = (const float*)d_in[5];
    const float* bv    = (const float*)d_in[6];
    const float* gamma = (const float*)d_in[7];
    float* out = (float*)d_out;

    // ws: qbf 256KB | kbf 256KB | xbf 2MB | Opart 8MB | Lp 256KB
    __hip_bfloat16* qbf   = (__hip_bfloat16*)d_ws;
    __hip_bfloat16* kbf   = qbf + (size_t)4 * NPIX * 8;
    __hip_bfloat16* xbf   = kbf + (size_t)4 * NPIX * 8;
    __hip_bfloat16* Opart = xbf + (size_t)4 * NPIX * 64;
    float* Lp = (float*)(Opart + (size_t)1024 * 4096);

    prep_kernel<<<256, 512, 0, stream>>>(x, Wq, bq, Wk, bk, qbf, kbf, xbf);
    flash_part_kernel<<<1024, 256, 0, stream>>>(qbf, kbf, xbf, Opart, Lp);
    merge_kernel<<<256, 512, 0, stream>>>(Opart, Lp, Wv, bv, x, gamma, out);
}

// Round 10
// 109.860 us; speedup vs baseline: 1.1455x; 1.0075x over previous
//
#include <hip/hip_runtime.h>
#include <hip/hip_bf16.h>
#include <math.h>

#define NPIX 4096

typedef __attribute__((ext_vector_type(8))) short s8;    // 8 x bf16 (4 VGPRs)
typedef __attribute__((ext_vector_type(16))) float f16v; // 16 x f32 (32x32 acc)

static __device__ __forceinline__ unsigned packbf2(float a, float b) {
    union { __hip_bfloat162 h; unsigned u; } x;
    x.h = __float22bfloat162_rn(make_float2(a, b));
    return x.u;
}
static __device__ __forceinline__ float2 unpackbf2(unsigned u) {
    float lo = __uint_as_float(u << 16);
    float hi = __uint_as_float(u & 0xffff0000u);
    return make_float2(lo, hi);
}

// ---------------------------------------------------------------------------
// Kernel 1: prep — q,k projections (bf16) + bf16 copy of x.
// R10: reverted to the R4-proven shape (256 thr, wave-uniform grp, 2 q + 2 k
// outputs per thread, bf162 stores); q pre-scaled by log2(e) for exp2 flash.
// (R5's 512-thr one-output variant coincided with a +6 µs total regression.)
// ---------------------------------------------------------------------------
__global__ __launch_bounds__(256) void prep_kernel(
    const float* __restrict__ x,
    const float* __restrict__ Wq, const float* __restrict__ bq,
    const float* __restrict__ Wk, const float* __restrict__ bk,
    __hip_bfloat16* __restrict__ qbf, __hip_bfloat16* __restrict__ kbf,
    __hip_bfloat16* __restrict__ xbf)
{
    __shared__ float Xp[64][65];
    int t = threadIdx.x;
    int lane = t & 63;
    int grp  = t >> 6;               // 0..3, wave-uniform
    int b  = blockIdx.x >> 6;
    int n0 = (blockIdx.x & 63) << 6;

    const float* xb = x + ((size_t)b << 18);
    __hip_bfloat16* xbb = xbf + ((size_t)b << 18);
#pragma unroll
    for (int u = 0; u < 16; ++u) {
        int c = grp + u * 4;
        float v = xb[((size_t)c << 12) + n0 + lane];
        Xp[c][lane] = v;
        xbb[((size_t)c << 12) + n0 + lane] = __float2bfloat16(v);
    }
    __syncthreads();

    int o0 = grp * 2, o1 = o0 + 1;
    float qa0 = bq[o0], qa1 = bq[o1], ka0 = bk[o0], ka1 = bk[o1];
    const float* wq0 = Wq + o0 * 64; const float* wq1 = Wq + o1 * 64;
    const float* wk0 = Wk + o0 * 64; const float* wk1 = Wk + o1 * 64;
#pragma unroll
    for (int c = 0; c < 64; ++c) {
        float xv = Xp[c][lane];
        qa0 = fmaf(wq0[c], xv, qa0);
        qa1 = fmaf(wq1[c], xv, qa1);
        ka0 = fmaf(wk0[c], xv, ka0);
        ka1 = fmaf(wk1[c], xv, ka1);
    }
    qa0 *= 1.4426950408889634f;        // fold log2(e): flash uses exp2
    qa1 *= 1.4426950408889634f;
    int pix = b * NPIX + n0 + lane;
    *(__hip_bfloat162*)(qbf + (size_t)pix * 8 + o0) =
        __float22bfloat162_rn(make_float2(qa0, qa1));
    *(__hip_bfloat162*)(kbf + (size_t)pix * 8 + o0) =
        __float22bfloat162_rn(make_float2(ka0, ka1));
}

// ---------------------------------------------------------------------------
// Kernel 2: flash partial. R10 vs R9: next-tile stage/K loads issued after
// barrier B so their latency hides under the P·x MFMA phase (consumed at the
// next barrier A's stage-write); stagger removed (R9: no effect).
// Scores + P·x both mfma_f32_32x32x16_bf16 (layouts HW-verified R8/R9).
// ---------------------------------------------------------------------------
__global__ __launch_bounds__(256, 4) void flash_part_kernel(
    const __hip_bfloat16* __restrict__ qbf, const __hip_bfloat16* __restrict__ kbf,
    const __hip_bfloat16* __restrict__ xbf,
    __hip_bfloat16* __restrict__ Opart, float* __restrict__ Lp)
{
    // phase A: Xs [64][136] bf16 @0 (17408B) | PTs [64 i][136 j] bf16 @17408
    // phase B: Osh [64 i][68] f32 @0 (17408B) | Lsh [4][64] @17408
    __shared__ __align__(16) char pool[34816];
    unsigned short* Xs  = (unsigned short*)pool;
    unsigned short* PTs = (unsigned short*)(pool + 17408);

    int t = threadIdx.x;
    int w    = t >> 6;
    int lane = t & 63;
    int l32  = lane & 31;
    int lh   = lane >> 5;            // k-half index in 32x32 frags
    int chalf = w & 1;               // P·x: c in [32*chalf, +32)
    int ihalf = w >> 1;              // P·x: i in [32*ihalf, +32)

    int blk  = blockIdx.x;
    int sId  = blk >> 8;
    int rest = blk & 255;
    int b    = rest >> 6;
    int i0   = (rest & 63) << 6;
    int jbase = sId << 10;

    const s8 zero8 = {0, 0, 0, 0, 0, 0, 0, 0};

    // Q B-frags: B[k=lh*8+r][n=l32 -> i=it32*32+l32]; lh=1 half zeroed (d<8)
    s8 qf[2];
#pragma unroll
    for (int it32 = 0; it32 < 2; ++it32) {
        s8 qv = *(const s8*)(qbf + ((size_t)(b * NPIX + i0 + it32 * 32 + l32) << 3));
        qf[it32] = (lh == 0) ? qv : zero8;
    }

    f16v acc;
#pragma unroll
    for (int r = 0; r < 16; ++r) acc[r] = 0.f;
    f16v zero16;
#pragma unroll
    for (int r = 0; r < 16; ++r) zero16[r] = 0.f;
    float l[2] = {0.f, 0.f};

    const __hip_bfloat16* kb = kbf + ((size_t)(b * NPIX) << 3);
    const unsigned short* xg = (const unsigned short*)xbf + ((size_t)b << 18);

    int c = t >> 2, seg = t & 3;

    // prefetch tile 0's stage data + K frag
    uint4 sv0, sv1, sv2, sv3;
    s8 kf;
    {
        const uint4* src = (const uint4*)(xg + ((size_t)c << 12) + jbase + seg * 32);
        sv0 = src[0]; sv1 = src[1]; sv2 = src[2]; sv3 = src[3];
        kf = *(const s8*)(kb + ((size_t)(jbase + w * 32 + l32) << 3));
    }

    for (int tile = 0; tile < 8; ++tile) {
        __syncthreads();   // A: previous tile's P·x readers done with Xs/PTs

        // stage-write Xs from prefetched regs
        {
            uint4* dst = (uint4*)(Xs + c * 136 + seg * 32);
            dst[0] = sv0; dst[1] = sv1; dst[2] = sv2; dst[3] = sv3;
        }

        // scores S^T[j][i] (32x32 per MFMA) + exp2 + publish to PTs[i][j]
#pragma unroll
        for (int it32 = 0; it32 < 2; ++it32) {
            f16v sv = __builtin_amdgcn_mfma_f32_32x32x16_bf16(kf, qf[it32], zero16, 0, 0, 0);
            int i = it32 * 32 + l32;
            float ls = 0.f;
#pragma unroll
            for (int g = 0; g < 4; ++g) {
                float e0 = exp2f(sv[4 * g + 0]);
                float e1 = exp2f(sv[4 * g + 1]);
                float e2 = exp2f(sv[4 * g + 2]);
                float e3 = exp2f(sv[4 * g + 3]);
                ls += (e0 + e1) + (e2 + e3);
                uint2 pk;
                pk.x = packbf2(e0, e1); pk.y = packbf2(e2, e3);
                // j = w*32 + 8g + 4lh + {0..3}
                *(uint2*)(PTs + i * 136 + w * 32 + 8 * g + 4 * lh) = pk;
            }
            l[it32] += ls;
        }
        __syncthreads();   // B: Xs + PTs ready

        // issue next tile's global loads — latency hides under P·x below
        {
            int jn = jbase + (((tile + 1) & 7) << 7);
            const uint4* src = (const uint4*)(xg + ((size_t)c << 12) + jn + seg * 32);
            sv0 = src[0]; sv1 = src[1]; sv2 = src[2]; sv3 = src[3];
            kf = *(const s8*)(kb + ((size_t)(jn + w * 32 + l32) << 3));
        }

        // P·x, 32x32x16: 8 k-chunks of 16 j
#pragma unroll
        for (int q = 0; q < 8; ++q) {
            s8 xf = *(const s8*)(Xs  + (chalf * 32 + l32) * 136 + q * 16 + lh * 8);
            s8 pf = *(const s8*)(PTs + (ihalf * 32 + l32) * 136 + q * 16 + lh * 8);
            acc = __builtin_amdgcn_mfma_f32_32x32x16_bf16(xf, pf, acc, 0, 0, 0);
        }
    }

    // ---------------- epilogue ----------------
    float* Osh = (float*)pool;                 // [64 i][68]
    float* Lsh = (float*)(pool + 17408);       // [4][64]

#pragma unroll
    for (int it32 = 0; it32 < 2; ++it32)
        l[it32] += __shfl_xor(l[it32], 32);

    __syncthreads();   // everyone done reading Xs/PTs
    if (lh == 0) {
#pragma unroll
        for (int it32 = 0; it32 < 2; ++it32)
            Lsh[w * 64 + it32 * 32 + l32] = l[it32];
    }
    // O write: wave w owns disjoint (c-half, i-half)
    {
        int i = ihalf * 32 + l32;
#pragma unroll
        for (int r = 0; r < 16; ++r) {
            int cc = chalf * 32 + (r & 3) + 8 * (r >> 2) + 4 * lh;
            Osh[i * 68 + cc] = acc[r];
        }
    }
    __syncthreads();

    if (t < 64)
        Lp[(size_t)blk * 64 + t] = Lsh[t] + Lsh[64 + t] + Lsh[128 + t] + Lsh[192 + t];

    // store partial O as bf16: thread t -> row i = t>>2, cols [(t&3)*16, +16)
    {
        int i = t >> 2, c0 = (t & 3) << 4;
        const float* src = Osh + i * 68 + c0;
        uint4 lo, hi;
        lo.x = packbf2(src[0], src[1]);   lo.y = packbf2(src[2], src[3]);
        lo.z = packbf2(src[4], src[5]);   lo.w = packbf2(src[6], src[7]);
        hi.x = packbf2(src[8], src[9]);   hi.y = packbf2(src[10], src[11]);
        hi.z = packbf2(src[12], src[13]); hi.w = packbf2(src[14], src[15]);
        uint4* dst = (uint4*)(Opart + (size_t)blk * 4096 + i * 64 + c0);
        dst[0] = lo; dst[1] = hi;
    }
}

// ---------------------------------------------------------------------------
// Kernel 3: merge. R10: 512 blocks x 256 thr (32-i tiles, 2 blocks/CU for
// latency hiding; was 256x512 = 1 block/CU). Same math.
// Flash blocks are 64-i with sId stride 256: fb = b*64 + (gi>>6), row gi&63.
// ---------------------------------------------------------------------------
__global__ __launch_bounds__(256) void merge_kernel(
    const __hip_bfloat16* __restrict__ Opart, const float* __restrict__ Lp,
    const float* __restrict__ Wv, const float* __restrict__ bv,
    const float* __restrict__ x, const float* __restrict__ gamma,
    float* __restrict__ out)
{
    __shared__ float Osh[32 * 68];
    __shared__ float Wvs[4096];
    __shared__ float LinvS[32];
    __shared__ float bvs[64];

    int t = threadIdx.x;
    int m  = blockIdx.x;
    int b  = m >> 7;
    int i0 = (m & 127) << 5;

    if (t < 32) {
        int gi = i0 + t;
        int fb = b * 64 + (gi >> 6);
        int r  = gi & 63;
        float lt = Lp[(size_t)(0 * 256 + fb) * 64 + r]
                 + Lp[(size_t)(1 * 256 + fb) * 64 + r]
                 + Lp[(size_t)(2 * 256 + fb) * 64 + r]
                 + Lp[(size_t)(3 * 256 + fb) * 64 + r];
        LinvS[t] = 1.0f / lt;
    }
    if (t < 64) bvs[t] = bv[t];
    {
        const float4* wsrc = (const float4*)Wv;
        float4* wdst = (float4*)Wvs;
#pragma unroll
        for (int u = 0; u < 4; ++u) wdst[t + u * 256] = wsrc[t + u * 256];
    }
    __syncthreads();

    // combine partials: thread t -> row i = t>>3 (0..31), cols [(t&7)*8, +8)
    {
        int i = t >> 3, c0 = (t & 7) << 3;
        int gi = i0 + i;
        int fb = b * 64 + (gi >> 6);
        int r  = gi & 63;
        float o[8];
#pragma unroll
        for (int k = 0; k < 8; ++k) o[k] = 0.f;
#pragma unroll
        for (int sId = 0; sId < 4; ++sId) {
            size_t base = (size_t)(sId * 256 + fb) * 4096 + r * 64 + c0;
            uint4 pk = *(const uint4*)(Opart + base);
            float2 e0 = unpackbf2(pk.x), e1 = unpackbf2(pk.y);
            float2 e2 = unpackbf2(pk.z), e3 = unpackbf2(pk.w);
            o[0] += e0.x; o[1] += e0.y; o[2] += e1.x; o[3] += e1.y;
            o[4] += e2.x; o[5] += e2.y; o[6] += e3.x; o[7] += e3.y;
        }
        float* dst = Osh + i * 68 + c0;
        *(float4*)(dst + 0) = make_float4(o[0], o[1], o[2], o[3]);
        *(float4*)(dst + 4) = make_float4(o[4], o[5], o[6], o[7]);
    }
    __syncthreads();

    // projection: i = t&31 (pixel), cg = t>>5 -> 8 output channels each
    {
        int i  = t & 31;
        int cg = t >> 5;
        float inv = LinvS[i];
        float res[8];
#pragma unroll
        for (int k = 0; k < 8; ++k) res[k] = 0.f;
#pragma unroll 4
        for (int cb = 0; cb < 16; ++cb) {
            float4 o = *(const float4*)(Osh + i * 68 + cb * 4);
#pragma unroll
            for (int k = 0; k < 8; ++k) {
                float4 wv4 = *(const float4*)(Wvs + (cg * 8 + k) * 64 + cb * 4);
                res[k] = fmaf(wv4.x, o.x, fmaf(wv4.y, o.y, fmaf(wv4.z, o.z, fmaf(wv4.w, o.w, res[k]))));
            }
        }
        float g = gamma[0];
        const float* xr = x + ((size_t)b << 18) + i0;
        float* outp = out + ((size_t)b << 18) + i0;
#pragma unroll
        for (int k = 0; k < 8; ++k) {
            int cch = cg * 8 + k;
            float attn = fmaf(res[k], inv, bvs[cch]);
            size_t off = ((size_t)cch << 12) + i;
            outp[off] = fmaf(g, attn, xr[off]);
        }
    }
}

extern "C" void kernel_launch(void* const* d_in, const int* in_sizes, int n_in,
                              void* d_out, int out_size, void* d_ws, size_t ws_size,
                              hipStream_t stream) {
    const float* x     = (const float*)d_in[0];
    const float* Wq    = (const float*)d_in[1];
    const float* bq    = (const float*)d_in[2];
    const float* Wk    = (const float*)d_in[3];
    const float* bk    = (const float*)d_in[4];
    const float* Wv    = (const float*)d_in[5];
    const float* bv    = (const float*)d_in[6];
    const float* gamma = (const float*)d_in[7];
    float* out = (float*)d_out;

    // ws: qbf 256KB | kbf 256KB | xbf 2MB | Opart 8MB | Lp 256KB
    __hip_bfloat16* qbf   = (__hip_bfloat16*)d_ws;
    __hip_bfloat16* kbf   = qbf + (size_t)4 * NPIX * 8;
    __hip_bfloat16* xbf   = kbf + (size_t)4 * NPIX * 8;
    __hip_bfloat16* Opart = xbf + (size_t)4 * NPIX * 64;
    float* Lp = (float*)(Opart + (size_t)1024 * 4096);

    prep_kernel<<<256, 256, 0, stream>>>(x, Wq, bq, Wk, bk, qbf, kbf, xbf);
    flash_part_kernel<<<1024, 256, 0, stream>>>(qbf, kbf, xbf, Opart, Lp);
    merge_kernel<<<512, 256, 0, stream>>>(Opart, Lp, Wv, bv, x, gamma, out);
}